// Round 1
// baseline (1837.698 us; speedup 1.0000x reference)
//
#include <hip/hip_runtime.h>
#include <hip/hip_cooperative_groups.h>
#include <math.h>

namespace cg = cooperative_groups;

#define L_SEQ 6464
#define DM 64
#define DI 128
#define DS 16
#define CHUNK 101
#define NCH 64
#define TSTR 108   // padded LDS stride: 27*16B aligned; 2-way bank alias only (free)

// ---------------- prologue: concat + pos, then @W_fcc + b_fcc ----------------
__global__ void k_embed(const float* __restrict__ DNA, const float* __restrict__ CpG,
                        const float* __restrict__ cell, const float* __restrict__ pos,
                        const float* __restrict__ Wfcc, const float* __restrict__ bfcc,
                        float* __restrict__ x0) {
    int l = blockIdx.x;
    int j = threadIdx.x;  // 64
    __shared__ float in64[64];
    float v;
    if (j < 16)       v = CpG[l * 16 + j];
    else if (j < 32)  v = cell[l * 16 + (j - 16)];
    else              v = DNA[l * 32 + (j - 32)];
    v += pos[l * 64 + j];
    in64[j] = v;
    __syncthreads();
    float acc = bfcc[j];
    for (int i = 0; i < 64; i++) acc += in64[i] * Wfcc[i * 64 + j];
    x0[(size_t)l * 64 + j] = acc;
}

// ------- fused: x@W_in (scalar-pipe x operand) + depthwise conv(+silu) both dirs
//         + xdbl (vec4, transposed Wxp) + dt/B/C; 16-row tiles -------
__global__ void __launch_bounds__(256) k_front(
        const float* __restrict__ x, const float* __restrict__ Win,
        const float* __restrict__ convw, const float* __restrict__ convb,
        const float* __restrict__ Wxp, const float* __restrict__ Wdt,
        const float* __restrict__ bdt, float* __restrict__ zb,
        float* __restrict__ xc, float* __restrict__ dt, float* __restrict__ BC) {
    __shared__ __align__(16) float s_xi[22][128];   // xi rows t0-3 .. t0+18
    __shared__ __align__(16) float s_xc[16][128];
    __shared__ float s_xd[16][36];
    __shared__ __align__(16) float s_wxpT[36][132]; // transposed W_xp, padded
    int t0 = blockIdx.x * 16;
    int tid = threadIdx.x;
    for (int i = tid; i < 36 * 128; i += 256) {
        int t = i >> 7, ii = i & 127;
        s_wxpT[t][ii] = Wxp[ii * 36 + t];
    }
    // ---- input GEMM: waves 0-1 do xi (22 rows incl. halo), waves 2-3 do z (16 rows)
    if (tid < 128) {
        int j = tid;
        float acc[22];
        #pragma unroll
        for (int r = 0; r < 22; r++) acc[r] = 0.f;
        for (int i0 = 0; i0 < 64; i0 += 8) {
            float w8[8];
            #pragma unroll
            for (int ii = 0; ii < 8; ii++) w8[ii] = Win[(i0 + ii) * 256 + j];
            #pragma unroll
            for (int r = 0; r < 22; r++) {
                int row = t0 - 3 + r;
                int rc = row < 0 ? 0 : (row >= L_SEQ ? L_SEQ - 1 : row);
                const float* xr = x + (size_t)rc * 64 + i0;   // uniform -> s_load
                #pragma unroll
                for (int ii = 0; ii < 8; ii++) acc[r] = fmaf(xr[ii], w8[ii], acc[r]);
            }
        }
        #pragma unroll
        for (int r = 0; r < 22; r++) {
            int row = t0 - 3 + r;
            s_xi[r][j] = (row < 0 || row >= L_SEQ) ? 0.f : acc[r];
        }
    } else {
        int j = tid - 128;
        float acc[16];
        #pragma unroll
        for (int r = 0; r < 16; r++) acc[r] = 0.f;
        for (int i0 = 0; i0 < 64; i0 += 8) {
            float w8[8];
            #pragma unroll
            for (int ii = 0; ii < 8; ii++) w8[ii] = Win[(i0 + ii) * 256 + 128 + j];
            #pragma unroll
            for (int r = 0; r < 16; r++) {
                const float* xr = x + (size_t)(t0 + r) * 64 + i0;   // uniform -> s_load
                #pragma unroll
                for (int ii = 0; ii < 8; ii++) acc[r] = fmaf(xr[ii], w8[ii], acc[r]);
            }
        }
        #pragma unroll
        for (int r = 0; r < 16; r++) zb[(size_t)(t0 + r) * 128 + j] = acc[r];
    }
    __syncthreads();
    for (int dir = 0; dir < 2; dir++) {
        // conv + silu
        for (int i = tid; i < 16 * 128; i += 256) {
            int rr = i >> 7, d = i & 127;
            int lr = rr + 3;
            float acc = convb[d];
            if (dir == 0) {
                #pragma unroll
                for (int k = 0; k < 4; k++) acc += convw[d * 4 + k] * s_xi[lr - 3 + k][d];
            } else {
                #pragma unroll
                for (int k = 0; k < 4; k++) acc += convw[d * 4 + k] * s_xi[lr + 3 - k][d];
            }
            float v = acc / (1.f + expf(-acc));
            s_xc[rr][d] = v;
            xc[((size_t)dir * L_SEQ + t0 + rr) * 128 + d] = v;
        }
        __syncthreads();
        // xdbl = xc @ W_xp (36 cols), vec4 over i
        for (int o = tid; o < 16 * 36; o += 256) {
            int rr = o / 36, t = o % 36;
            float acc = 0.f;
            #pragma unroll 8
            for (int i = 0; i < 128; i += 4) {
                const float4 xv = *(const float4*)&s_xc[rr][i];
                const float4 wv = *(const float4*)&s_wxpT[t][i];
                acc = fmaf(xv.x, wv.x, acc);
                acc = fmaf(xv.y, wv.y, acc);
                acc = fmaf(xv.z, wv.z, acc);
                acc = fmaf(xv.w, wv.w, acc);
            }
            s_xd[rr][t] = acc;
        }
        __syncthreads();
        // dt = softplus(xdbl[:, :4] @ W_dt + b_dt); B,C passthrough
        for (int o = tid; o < 16 * 128; o += 256) {
            int rr = o >> 7, d = o & 127;
            float pre = bdt[d];
            #pragma unroll
            for (int r = 0; r < 4; r++) pre += s_xd[rr][r] * Wdt[r * 128 + d];
            float dtv = (pre > 20.f) ? pre : log1pf(expf(pre));
            dt[((size_t)dir * L_SEQ + t0 + rr) * 128 + d] = dtv;
        }
        for (int o = tid; o < 16 * 32; o += 256) {
            int rr = o >> 5, w = o & 31;
            BC[((size_t)dir * L_SEQ + t0 + rr) * 32 + w] = s_xd[rr][4 + w];
        }
        __syncthreads();
    }
}

// ---------------- DPP 16-lane row rotate ----------------
template<int CTRL>
__device__ __forceinline__ float ror16f(float v) {
    return __int_as_float(__builtin_amdgcn_update_dpp(0, __float_as_int(v), CTRL, 0xf, 0xf, true));
}

// ------- merged scan: stage once, pass A (carries), grid.sync, lookback, pass B (y) -------
__global__ void __launch_bounds__(256, 4) k_scan(
        const float* __restrict__ dt, const float* __restrict__ xc,
        const float* __restrict__ BC, const float* __restrict__ Alog,
        const float* __restrict__ Dres, float* __restrict__ cA,
        float* __restrict__ cB, float* __restrict__ y) {
    __shared__ __align__(16) float s_dt[16 * TSTR];   // becomes y in-place in pass B
    __shared__ __align__(16) float s_xc[16 * TSTR];
    __shared__ __align__(16) float s_B [16 * TSTR];
    __shared__ __align__(16) float s_C [16 * TSTR];
    int bxd = blockIdx.x;   // d-group (8)
    int c   = blockIdx.y;   // chunk (64)
    int dir = blockIdx.z;   // 2
    int tid = threadIdx.x;
    int s = tid & 15, dl = tid >> 4;
    int d0 = bxd * 16;
    const float* dtp = dt + (size_t)dir * L_SEQ * DI;
    const float* xcp = xc + (size_t)dir * L_SEQ * DI;
    const float* bcp = BC + (size_t)dir * L_SEQ * 32;
    float* yp = y + (size_t)dir * L_SEQ * DI;
    int t0 = c * CHUNK;
    int slab0 = dir ? (L_SEQ - CHUNK - t0) : t0;   // contiguous physical row slab
    for (int i = tid; i < CHUNK * 4; i += 256) {
        int ro = i >> 2, q = i & 3;
        int row = slab0 + ro;
        int tl = dir ? (CHUNK - 1 - ro) : ro;
        float4 dv = *(const float4*)&dtp[(size_t)row * DI + d0 + 4 * q];
        float4 xv = *(const float4*)&xcp[(size_t)row * DI + d0 + 4 * q];
        float4 bv = *(const float4*)&bcp[(size_t)row * 32 + 4 * q];
        float4 cv = *(const float4*)&bcp[(size_t)row * 32 + 16 + 4 * q];
        s_dt[(4 * q + 0) * TSTR + tl] = dv.x; s_dt[(4 * q + 1) * TSTR + tl] = dv.y;
        s_dt[(4 * q + 2) * TSTR + tl] = dv.z; s_dt[(4 * q + 3) * TSTR + tl] = dv.w;
        s_xc[(4 * q + 0) * TSTR + tl] = xv.x; s_xc[(4 * q + 1) * TSTR + tl] = xv.y;
        s_xc[(4 * q + 2) * TSTR + tl] = xv.z; s_xc[(4 * q + 3) * TSTR + tl] = xv.w;
        s_B [(4 * q + 0) * TSTR + tl] = bv.x; s_B [(4 * q + 1) * TSTR + tl] = bv.y;
        s_B [(4 * q + 2) * TSTR + tl] = bv.z; s_B [(4 * q + 3) * TSTR + tl] = bv.w;
        s_C [(4 * q + 0) * TSTR + tl] = cv.x; s_C [(4 * q + 1) * TSTR + tl] = cv.y;
        s_C [(4 * q + 2) * TSTR + tl] = cv.z; s_C [(4 * q + 3) * TSTR + tl] = cv.w;
    }
    __syncthreads();
    float A = -expf(Alog[d0 * 16 + tid]);
    const int tb = dl * TSTR;
    const int sbb = s * TSTR;
    // ---- pass A: per-chunk (a_prod, h_end)
    {
        float h = 0.f, ap = 1.f;
        int tl = 0;
        for (int u = 0; u < 25; u++, tl += 4) {
            float4 dq = *(const float4*)&s_dt[tb + tl];
            float4 xq = *(const float4*)&s_xc[tb + tl];
            float4 bq = *(const float4*)&s_B [sbb + tl];
            float a;
            a = __expf(dq.x * A); h = fmaf(a, h, dq.x * xq.x * bq.x); ap *= a;
            a = __expf(dq.y * A); h = fmaf(a, h, dq.y * xq.y * bq.y); ap *= a;
            a = __expf(dq.z * A); h = fmaf(a, h, dq.z * xq.z * bq.z); ap *= a;
            a = __expf(dq.w * A); h = fmaf(a, h, dq.w * xq.w * bq.w); ap *= a;
        }
        {
            float dv = s_dt[tb + 100], xv = s_xc[tb + 100], bv = s_B[sbb + 100];
            float a = __expf(dv * A); h = fmaf(a, h, dv * xv * bv); ap *= a;
        }
        size_t o = (((size_t)dir * NCH + c) << 11) + (size_t)bxd * 256 + tid;
        cA[o] = ap;
        cB[o] = h;
    }
    __threadfence();
    cg::this_grid().sync();
    // ---- lookback: fold predecessor carries (all visible after grid sync)
    float carry = 0.f;
    {
        int cc = 0;
        while (cc < c) {
            int n = (c - cc < 8) ? (c - cc) : 8;
            float av[8], bv[8];
            for (int j = 0; j < n; j++) {
                size_t oo = (((size_t)dir * NCH + (cc + j)) << 11) + (size_t)bxd * 256 + tid;
                av[j] = cA[oo];
                bv[j] = cB[oo];
            }
            for (int j = 0; j < n; j++) carry = fmaf(av[j], carry, bv[j]);
            cc += n;
        }
    }
    // ---- pass B: replay with carry; y via in-place s_dt reuse (LDS still staged)
    float Dv = Dres[d0 + dl];
    float h = carry;
    int tl = 0;
    for (int u = 0; u < 25; u++, tl += 4) {
        float4 dq = *(const float4*)&s_dt[tb + tl];
        float4 xq = *(const float4*)&s_xc[tb + tl];
        float4 bq = *(const float4*)&s_B [sbb + tl];
        float4 cq = *(const float4*)&s_C [sbb + tl];
        #pragma unroll
        for (int k = 0; k < 4; k++) {
            float dv = (k == 0) ? dq.x : (k == 1) ? dq.y : (k == 2) ? dq.z : dq.w;
            float xv = (k == 0) ? xq.x : (k == 1) ? xq.y : (k == 2) ? xq.z : xq.w;
            float bv = (k == 0) ? bq.x : (k == 1) ? bq.y : (k == 2) ? bq.z : bq.w;
            float cv = (k == 0) ? cq.x : (k == 1) ? cq.y : (k == 2) ? cq.z : cq.w;
            float a = __expf(dv * A);
            h = fmaf(a, h, dv * xv * bv);
            float val = h * cv;
            val += ror16f<0x121>(val);
            val += ror16f<0x122>(val);
            val += ror16f<0x124>(val);
            val += ror16f<0x128>(val);
            if (s == 0) s_dt[tb + tl + k] = val + xv * Dv;  // in-place y (own-warp row)
        }
    }
    {
        float dv = s_dt[tb + 100], xv = s_xc[tb + 100];
        float bv = s_B[sbb + 100], cv = s_C[sbb + 100];
        float a = __expf(dv * A);
        h = fmaf(a, h, dv * xv * bv);
        float val = h * cv;
        val += ror16f<0x121>(val);
        val += ror16f<0x122>(val);
        val += ror16f<0x124>(val);
        val += ror16f<0x128>(val);
        if (s == 0) s_dt[tb + 100] = val + xv * Dv;
    }
    __syncthreads();
    for (int i = tid; i < CHUNK * 4; i += 256) {
        int ro = i >> 2, q = i & 3;
        int row = slab0 + ro;
        int tl2 = dir ? (CHUNK - 1 - ro) : ro;
        float4 v;
        v.x = s_dt[(4 * q + 0) * TSTR + tl2];
        v.y = s_dt[(4 * q + 1) * TSTR + tl2];
        v.z = s_dt[(4 * q + 2) * TSTR + tl2];
        v.w = s_dt[(4 * q + 3) * TSTR + tl2];
        *(float4*)&yp[(size_t)row * DI + d0 + 4 * q] = v;
    }
}

// ------- out-GEMM + silu(z) gate + residual + layernorm + permute; 4 rows/block -------
__global__ void __launch_bounds__(256) k_outln(
        const float* __restrict__ x, const float* __restrict__ y,
        const float* __restrict__ zb, const float* __restrict__ Wout,
        const float* __restrict__ lng, const float* __restrict__ lnb,
        float* __restrict__ xnext, int permMode) {
    __shared__ float s_g[4][128];
    int w = threadIdx.x >> 6;        // wave id (row within block)
    int j = threadIdx.x & 63;
    int l = blockIdx.x * 4 + w;
    float z1 = zb[(size_t)l * 128 + j];
    float z2 = zb[(size_t)l * 128 + 64 + j];
    float sz1 = z1 / (1.f + expf(-z1));
    float sz2 = z2 / (1.f + expf(-z2));
    s_g[w][j]      = 0.5f * (y[(size_t)l * 128 + j] + y[(size_t)(L_SEQ + l) * 128 + j]) * sz1;
    s_g[w][j + 64] = 0.5f * (y[(size_t)l * 128 + 64 + j] + y[(size_t)(L_SEQ + l) * 128 + 64 + j]) * sz2;
    __syncthreads();
    float acc = x[(size_t)l * 64 + j];
    for (int i = 0; i < 128; i++) acc += s_g[w][i] * Wout[i * 64 + j];
    float m = acc;
    for (int o = 32; o >= 1; o >>= 1) m += __shfl_xor(m, o);
    m *= (1.f / 64.f);
    float dv = acc - m;
    float v = dv * dv;
    for (int o = 32; o >= 1; o >>= 1) v += __shfl_xor(v, o);
    v *= (1.f / 64.f);
    float out = dv * rsqrtf(v + 1e-5f) * lng[j] + lnb[j];
    int l2;
    if (permMode == 0) l2 = (l % 64) * 101 + (l / 64);   // (s,c)->(c,s)
    else               l2 = (l % 101) * 64 + (l / 101);  // (c,s)->(s,c)
    xnext[(size_t)l2 * 64 + j] = out;
}

// ---------------- epilogue ----------------
__global__ void k_epilogue(const float* __restrict__ x, const float* __restrict__ Wfc,
                           const float* __restrict__ bfc, const float* __restrict__ ytrue,
                           const int* __restrict__ halfwin, const int* __restrict__ rows,
                           float* __restrict__ out) {
    int k = threadIdx.x;  // 64
    int hw = halfwin[0];
    int c = rows[k];
    const float* xr = x + ((size_t)hw * 64 + c) * 64;
    float acc = bfc[0];
    for (int i = 0; i < 64; i++) acc += xr[i] * Wfc[i];
    float s = 1.f / (1.f + expf(-acc));
    float r = 1.f - fabsf(ytrue[k] - s);
    out[k] = r;
}

extern "C" void kernel_launch(void* const* d_in, const int* in_sizes, int n_in,
                              void* d_out, int out_size, void* d_ws, size_t ws_size,
                              hipStream_t stream) {
    const float* DNA   = (const float*)d_in[0];
    const float* CpG   = (const float*)d_in[1];
    const float* cel   = (const float*)d_in[2];
    const float* pos   = (const float*)d_in[3];
    const float* ytrue = (const float*)d_in[4];
    const float* Wfcc  = (const float*)d_in[5];
    const float* bfcc  = (const float*)d_in[6];
    const float* Win   = (const float*)d_in[7];
    const float* convw = (const float*)d_in[8];
    const float* convb = (const float*)d_in[9];
    const float* Wxp   = (const float*)d_in[10];
    const float* Wdt   = (const float*)d_in[11];
    const float* bdt   = (const float*)d_in[12];
    const float* Alog  = (const float*)d_in[13];
    const float* Dres  = (const float*)d_in[14];
    const float* Wout  = (const float*)d_in[15];
    const float* lng   = (const float*)d_in[16];
    const float* lnb   = (const float*)d_in[17];
    const float* Wfc   = (const float*)d_in[18];
    const float* bfc   = (const float*)d_in[19];
    const int* halfwin = (const int*)d_in[20];
    const int* rows    = (const int*)d_in[21];

    float* ws = (float*)d_ws;
    size_t off = 0;
    float* x0  = ws + off; off += (size_t)L_SEQ * 64;
    float* x1  = ws + off; off += (size_t)L_SEQ * 64;
    float* zbb = ws + off; off += (size_t)L_SEQ * 128;
    float* xcb = ws + off; off += (size_t)2 * L_SEQ * 128;
    float* dtb = ws + off; off += (size_t)2 * L_SEQ * 128;
    float* BCb = ws + off; off += (size_t)2 * L_SEQ * 32;
    float* yb  = ws + off; off += (size_t)2 * L_SEQ * 128;
    float* cAb = ws + off; off += (size_t)2 * NCH * 2048;
    float* cBb = ws + off; off += (size_t)2 * NCH * 2048;

    k_embed<<<L_SEQ, 64, 0, stream>>>(DNA, CpG, cel, pos, Wfcc, bfcc, x0);

    float* xcur = x0;
    float* xnxt = x1;
    for (int sb = 0; sb < 8; sb++) {
        k_front<<<L_SEQ / 16, 256, 0, stream>>>(xcur, Win, convw, convb, Wxp, Wdt, bdt,
                                                zbb, xcb, dtb, BCb);
        {
            const float* a0 = dtb;  const float* a1 = xcb;  const float* a2 = BCb;
            const float* a3 = Alog; const float* a4 = Dres;
            float* a5 = cAb; float* a6 = cBb; float* a7 = yb;
            void* args[8] = {&a0, &a1, &a2, &a3, &a4, &a5, &a6, &a7};
            hipLaunchCooperativeKernel(k_scan, dim3(8, NCH, 2), dim3(256, 1, 1),
                                       args, 0, stream);
        }
        k_outln<<<L_SEQ / 4, 256, 0, stream>>>(xcur, yb, zbb, Wout, lng, lnb, xnxt,
                                               (sb % 2 == 0) ? 0 : 1);
        float* tmp = xcur; xcur = xnxt; xnxt = tmp;
    }

    k_epilogue<<<1, 64, 0, stream>>>(xcur, Wfc, bfc, ytrue, halfwin, rows, (float*)d_out);
}

// Round 2
// 852.950 us; speedup vs baseline: 2.1545x; 2.1545x over previous
//
#include <hip/hip_runtime.h>
#include <math.h>

#define L_SEQ 6464
#define DM 64
#define DI 128
#define DS 16
#define CHUNK 101
#define NCH 64
#define TSTR 108   // padded LDS stride: 27*16B aligned; 2-way bank alias only (free)

// ---------------- prologue: concat + pos, then @W_fcc + b_fcc ----------------
__global__ void k_embed(const float* __restrict__ DNA, const float* __restrict__ CpG,
                        const float* __restrict__ cell, const float* __restrict__ pos,
                        const float* __restrict__ Wfcc, const float* __restrict__ bfcc,
                        float* __restrict__ x0) {
    int l = blockIdx.x;
    int j = threadIdx.x;  // 64
    __shared__ float in64[64];
    float v;
    if (j < 16)       v = CpG[l * 16 + j];
    else if (j < 32)  v = cell[l * 16 + (j - 16)];
    else              v = DNA[l * 32 + (j - 32)];
    v += pos[l * 64 + j];
    in64[j] = v;
    __syncthreads();
    float acc = bfcc[j];
    for (int i = 0; i < 64; i++) acc += in64[i] * Wfcc[i * 64 + j];
    x0[(size_t)l * 64 + j] = acc;
}

// ---------------- xz = x @ W_in : 8 rows/block (first layer only) ----------------
__global__ void __launch_bounds__(256) k_gemm_in(const float* __restrict__ x,
                                                 const float* __restrict__ Win,
                                                 float* __restrict__ xz) {
    __shared__ float s_x[8][64];
    int t0 = blockIdx.x * 8;
    int tid = threadIdx.x;
    for (int i = tid; i < 8 * 64; i += 256) {
        int rr = i >> 6, c = i & 63;
        s_x[rr][c] = x[(size_t)(t0 + rr) * 64 + c];
    }
    __syncthreads();
    int j = tid;  // 256 cols
    float acc[8];
    #pragma unroll
    for (int r = 0; r < 8; r++) acc[r] = 0.f;
    for (int i = 0; i < 64; i++) {
        float w = Win[i * 256 + j];
        #pragma unroll
        for (int r = 0; r < 8; r++) acc[r] = fmaf(s_x[r][i], w, acc[r]);
    }
    #pragma unroll
    for (int r = 0; r < 8; r++) xz[(size_t)(t0 + r) * 256 + j] = acc[r];
}

// ------- fused depthwise conv(+silu) both dirs + xdbl (vec4) + dt/B/C, 16-row tiles -------
__global__ void __launch_bounds__(256) k_convdt(
        const float* __restrict__ xz, const float* __restrict__ convw,
        const float* __restrict__ convb, const float* __restrict__ Wxp,
        const float* __restrict__ Wdt, const float* __restrict__ bdt,
        float* __restrict__ xc, float* __restrict__ dt, float* __restrict__ BC) {
    __shared__ __align__(16) float s_xi[22][128];   // rows t0-3 .. t0+18
    __shared__ __align__(16) float s_xc[16][128];
    __shared__ float s_xd[16][36];
    __shared__ __align__(16) float s_wxpT[36][132]; // transposed W_xp, padded
    int t0 = blockIdx.x * 16;
    int tid = threadIdx.x;
    for (int i = tid; i < 36 * 128; i += 256) {
        int t = i >> 7, ii = i & 127;
        s_wxpT[t][ii] = Wxp[ii * 36 + t];
    }
    for (int i = tid; i < 22 * 32; i += 256) {
        int rr = i >> 5, q = i & 31;
        int r = t0 - 3 + rr;
        float4 v = make_float4(0.f, 0.f, 0.f, 0.f);
        if (r >= 0 && r < L_SEQ) v = *(const float4*)&xz[(size_t)r * 256 + 4 * q];
        s_xi[rr][4 * q + 0] = v.x;
        s_xi[rr][4 * q + 1] = v.y;
        s_xi[rr][4 * q + 2] = v.z;
        s_xi[rr][4 * q + 3] = v.w;
    }
    __syncthreads();
    for (int dir = 0; dir < 2; dir++) {
        // conv + silu
        for (int i = tid; i < 16 * 128; i += 256) {
            int rr = i >> 7, d = i & 127;
            int lr = rr + 3;  // local index of central row
            float acc = convb[d];
            if (dir == 0) {
                #pragma unroll
                for (int k = 0; k < 4; k++) acc += convw[d * 4 + k] * s_xi[lr - 3 + k][d];
            } else {
                #pragma unroll
                for (int k = 0; k < 4; k++) acc += convw[d * 4 + k] * s_xi[lr + 3 - k][d];
            }
            float v = acc / (1.f + expf(-acc));
            s_xc[rr][d] = v;
            xc[((size_t)dir * L_SEQ + t0 + rr) * 128 + d] = v;
        }
        __syncthreads();
        // xdbl = xc @ W_xp (36 cols), vec4 over i (same summation order as scalar)
        for (int o = tid; o < 16 * 36; o += 256) {
            int rr = o / 36, t = o % 36;
            float acc = 0.f;
            #pragma unroll 8
            for (int i = 0; i < 128; i += 4) {
                const float4 xv = *(const float4*)&s_xc[rr][i];
                const float4 wv = *(const float4*)&s_wxpT[t][i];
                acc = fmaf(xv.x, wv.x, acc);
                acc = fmaf(xv.y, wv.y, acc);
                acc = fmaf(xv.z, wv.z, acc);
                acc = fmaf(xv.w, wv.w, acc);
            }
            s_xd[rr][t] = acc;
        }
        __syncthreads();
        // dt = softplus(xdbl[:, :4] @ W_dt + b_dt); B,C passthrough
        for (int o = tid; o < 16 * 128; o += 256) {
            int rr = o >> 7, d = o & 127;
            float pre = bdt[d];
            #pragma unroll
            for (int r = 0; r < 4; r++) pre += s_xd[rr][r] * Wdt[r * 128 + d];
            float dtv = (pre > 20.f) ? pre : log1pf(expf(pre));
            dt[((size_t)dir * L_SEQ + t0 + rr) * 128 + d] = dtv;
        }
        for (int o = tid; o < 16 * 32; o += 256) {
            int rr = o >> 5, w = o & 31;
            BC[((size_t)dir * L_SEQ + t0 + rr) * 32 + w] = s_xd[rr][4 + w];
        }
        __syncthreads();
    }
}

// ---------------- DPP 16-lane row rotate ----------------
template<int CTRL>
__device__ __forceinline__ float ror16f(float v) {
    return __int_as_float(__builtin_amdgcn_update_dpp(0, __float_as_int(v), CTRL, 0xf, 0xf, true));
}

// ---------------- scan pass 1: staged per-chunk (a_prod, h_end) ----------------
__global__ void __launch_bounds__(256) k_scan1s(
        const float* __restrict__ dt, const float* __restrict__ xc,
        const float* __restrict__ BC, const float* __restrict__ Alog,
        float* __restrict__ cA, float* __restrict__ cB) {
    __shared__ __align__(16) float s_dt[16 * TSTR];
    __shared__ __align__(16) float s_xc[16 * TSTR];
    __shared__ __align__(16) float s_B [16 * TSTR];
    int bxd = blockIdx.x;   // d-group (8)
    int c   = blockIdx.y;   // chunk (64)
    int dir = blockIdx.z;   // 2
    int tid = threadIdx.x;
    int s = tid & 15, dl = tid >> 4;
    int d0 = bxd * 16;
    const float* dtp = dt + (size_t)dir * L_SEQ * DI;
    const float* xcp = xc + (size_t)dir * L_SEQ * DI;
    const float* bcp = BC + (size_t)dir * L_SEQ * 32;
    int t0 = c * CHUNK;
    int slab0 = dir ? (L_SEQ - CHUNK - t0) : t0;   // contiguous physical row slab
    for (int i = tid; i < CHUNK * 4; i += 256) {
        int ro = i >> 2, q = i & 3;
        int row = slab0 + ro;
        int tl = dir ? (CHUNK - 1 - ro) : ro;
        float4 dv = *(const float4*)&dtp[(size_t)row * DI + d0 + 4 * q];
        float4 xv = *(const float4*)&xcp[(size_t)row * DI + d0 + 4 * q];
        float4 bv = *(const float4*)&bcp[(size_t)row * 32 + 4 * q];
        s_dt[(4 * q + 0) * TSTR + tl] = dv.x; s_dt[(4 * q + 1) * TSTR + tl] = dv.y;
        s_dt[(4 * q + 2) * TSTR + tl] = dv.z; s_dt[(4 * q + 3) * TSTR + tl] = dv.w;
        s_xc[(4 * q + 0) * TSTR + tl] = xv.x; s_xc[(4 * q + 1) * TSTR + tl] = xv.y;
        s_xc[(4 * q + 2) * TSTR + tl] = xv.z; s_xc[(4 * q + 3) * TSTR + tl] = xv.w;
        s_B [(4 * q + 0) * TSTR + tl] = bv.x; s_B [(4 * q + 1) * TSTR + tl] = bv.y;
        s_B [(4 * q + 2) * TSTR + tl] = bv.z; s_B [(4 * q + 3) * TSTR + tl] = bv.w;
    }
    __syncthreads();
    float A = -expf(Alog[d0 * 16 + tid]);
    const int tb = dl * TSTR;
    const int sbb = s * TSTR;
    float h = 0.f, ap = 1.f;
    int tl = 0;
    for (int u = 0; u < 25; u++, tl += 4) {
        float4 dq = *(const float4*)&s_dt[tb + tl];
        float4 xq = *(const float4*)&s_xc[tb + tl];
        float4 bq = *(const float4*)&s_B [sbb + tl];
        float a;
        a = __expf(dq.x * A); h = fmaf(a, h, dq.x * xq.x * bq.x); ap *= a;
        a = __expf(dq.y * A); h = fmaf(a, h, dq.y * xq.y * bq.y); ap *= a;
        a = __expf(dq.z * A); h = fmaf(a, h, dq.z * xq.z * bq.z); ap *= a;
        a = __expf(dq.w * A); h = fmaf(a, h, dq.w * xq.w * bq.w); ap *= a;
    }
    {
        float dv = s_dt[tb + 100], xv = s_xc[tb + 100], bv = s_B[sbb + 100];
        float a = __expf(dv * A); h = fmaf(a, h, dv * xv * bv); ap *= a;
    }
    size_t o = (((size_t)dir * NCH + c) << 11) + (size_t)bxd * 256 + tid;
    cA[o] = ap;
    cB[o] = h;
}

// ------- scan pass 2: lookback (stream-ordered plain loads) + replay; y via s_dt reuse -------
__global__ void __launch_bounds__(256) k_scan3s(
        const float* __restrict__ dt, const float* __restrict__ xc,
        const float* __restrict__ BC, const float* __restrict__ Alog,
        const float* __restrict__ Dres, const float* __restrict__ cA,
        const float* __restrict__ cB, float* __restrict__ y) {
    __shared__ __align__(16) float s_dt[16 * TSTR];   // becomes y in-place
    __shared__ __align__(16) float s_xc[16 * TSTR];
    __shared__ __align__(16) float s_B [16 * TSTR];
    __shared__ __align__(16) float s_C [16 * TSTR];
    int bxd = blockIdx.x;
    int c   = blockIdx.y;
    int dir = blockIdx.z;
    int tid = threadIdx.x;
    int s = tid & 15, dl = tid >> 4;
    int d0 = bxd * 16;
    const float* dtp = dt + (size_t)dir * L_SEQ * DI;
    const float* xcp = xc + (size_t)dir * L_SEQ * DI;
    const float* bcp = BC + (size_t)dir * L_SEQ * 32;
    float* yp = y + (size_t)dir * L_SEQ * DI;
    int t0 = c * CHUNK;
    int slab0 = dir ? (L_SEQ - CHUNK - t0) : t0;
    for (int i = tid; i < CHUNK * 4; i += 256) {
        int ro = i >> 2, q = i & 3;
        int row = slab0 + ro;
        int tl = dir ? (CHUNK - 1 - ro) : ro;
        float4 dv = *(const float4*)&dtp[(size_t)row * DI + d0 + 4 * q];
        float4 xv = *(const float4*)&xcp[(size_t)row * DI + d0 + 4 * q];
        float4 bv = *(const float4*)&bcp[(size_t)row * 32 + 4 * q];
        float4 cv = *(const float4*)&bcp[(size_t)row * 32 + 16 + 4 * q];
        s_dt[(4 * q + 0) * TSTR + tl] = dv.x; s_dt[(4 * q + 1) * TSTR + tl] = dv.y;
        s_dt[(4 * q + 2) * TSTR + tl] = dv.z; s_dt[(4 * q + 3) * TSTR + tl] = dv.w;
        s_xc[(4 * q + 0) * TSTR + tl] = xv.x; s_xc[(4 * q + 1) * TSTR + tl] = xv.y;
        s_xc[(4 * q + 2) * TSTR + tl] = xv.z; s_xc[(4 * q + 3) * TSTR + tl] = xv.w;
        s_B [(4 * q + 0) * TSTR + tl] = bv.x; s_B [(4 * q + 1) * TSTR + tl] = bv.y;
        s_B [(4 * q + 2) * TSTR + tl] = bv.z; s_B [(4 * q + 3) * TSTR + tl] = bv.w;
        s_C [(4 * q + 0) * TSTR + tl] = cv.x; s_C [(4 * q + 1) * TSTR + tl] = cv.y;
        s_C [(4 * q + 2) * TSTR + tl] = cv.z; s_C [(4 * q + 3) * TSTR + tl] = cv.w;
    }
    // lookback: fold predecessor carries (written by k_scan1s; stream-ordered)
    float carry = 0.f;
    int cc = 0;
    while (cc < c) {
        int n = (c - cc < 8) ? (c - cc) : 8;
        float av[8], bv[8];
        for (int j = 0; j < n; j++) {
            size_t oo = (((size_t)dir * NCH + (cc + j)) << 11) + (size_t)bxd * 256 + tid;
            av[j] = cA[oo];
            bv[j] = cB[oo];
        }
        for (int j = 0; j < n; j++) carry = fmaf(av[j], carry, bv[j]);
        cc += n;
    }
    __syncthreads();

    float A = -expf(Alog[d0 * 16 + tid]);
    float Dv = Dres[d0 + dl];
    const int tb = dl * TSTR;
    const int sbb = s * TSTR;
    float h = carry;
    int tl = 0;
    for (int u = 0; u < 25; u++, tl += 4) {
        float4 dq = *(const float4*)&s_dt[tb + tl];
        float4 xq = *(const float4*)&s_xc[tb + tl];
        float4 bq = *(const float4*)&s_B [sbb + tl];
        float4 cq = *(const float4*)&s_C [sbb + tl];
        #pragma unroll
        for (int k = 0; k < 4; k++) {
            float dv = (k == 0) ? dq.x : (k == 1) ? dq.y : (k == 2) ? dq.z : dq.w;
            float xv = (k == 0) ? xq.x : (k == 1) ? xq.y : (k == 2) ? xq.z : xq.w;
            float bv = (k == 0) ? bq.x : (k == 1) ? bq.y : (k == 2) ? bq.z : bq.w;
            float cv = (k == 0) ? cq.x : (k == 1) ? cq.y : (k == 2) ? cq.z : cq.w;
            float a = __expf(dv * A);
            h = fmaf(a, h, dv * xv * bv);
            float val = h * cv;
            val += ror16f<0x121>(val);
            val += ror16f<0x122>(val);
            val += ror16f<0x124>(val);
            val += ror16f<0x128>(val);
            if (s == 0) s_dt[tb + tl + k] = val + xv * Dv;  // in-place y (read-before-write in wave)
        }
    }
    {
        float dv = s_dt[tb + 100], xv = s_xc[tb + 100];
        float bv = s_B[sbb + 100], cv = s_C[sbb + 100];
        float a = __expf(dv * A);
        h = fmaf(a, h, dv * xv * bv);
        float val = h * cv;
        val += ror16f<0x121>(val);
        val += ror16f<0x122>(val);
        val += ror16f<0x124>(val);
        val += ror16f<0x128>(val);
        if (s == 0) s_dt[tb + 100] = val + xv * Dv;
    }
    __syncthreads();
    for (int i = tid; i < CHUNK * 4; i += 256) {
        int ro = i >> 2, q = i & 3;
        int row = slab0 + ro;
        int tl = dir ? (CHUNK - 1 - ro) : ro;
        float4 v;
        v.x = s_dt[(4 * q + 0) * TSTR + tl];
        v.y = s_dt[(4 * q + 1) * TSTR + tl];
        v.z = s_dt[(4 * q + 2) * TSTR + tl];
        v.w = s_dt[(4 * q + 3) * TSTR + tl];
        *(float4*)&yp[(size_t)row * DI + d0 + 4 * q] = v;
    }
}

// ------- out-GEMM + gate + residual + layernorm + permute + NEXT-LAYER xz; 4 rows/block -------
__global__ void __launch_bounds__(256) k_outln(
        const float* __restrict__ x, const float* __restrict__ y,
        const float* __restrict__ xz, const float* __restrict__ Wout,
        const float* __restrict__ Win, const float* __restrict__ lng,
        const float* __restrict__ lnb, float* __restrict__ xnext,
        float* __restrict__ xznext, int permMode, int doXz) {
    __shared__ float s_g[4][128];
    __shared__ float s_out[4][64];
    __shared__ int s_l2[4];
    int tid = threadIdx.x;
    int w = tid >> 6;        // wave id (row within block)
    int j = tid & 63;
    int l = blockIdx.x * 4 + w;
    float z1 = xz[(size_t)l * 256 + 128 + j];
    float z2 = xz[(size_t)l * 256 + 192 + j];
    float sz1 = z1 / (1.f + expf(-z1));
    float sz2 = z2 / (1.f + expf(-z2));
    s_g[w][j]      = 0.5f * (y[(size_t)l * 128 + j] + y[(size_t)(L_SEQ + l) * 128 + j]) * sz1;
    s_g[w][j + 64] = 0.5f * (y[(size_t)l * 128 + 64 + j] + y[(size_t)(L_SEQ + l) * 128 + 64 + j]) * sz2;
    __syncthreads();
    float acc = x[(size_t)l * 64 + j];
    for (int i = 0; i < 128; i++) acc += s_g[w][i] * Wout[i * 64 + j];
    float m = acc;
    for (int o = 32; o >= 1; o >>= 1) m += __shfl_xor(m, o);
    m *= (1.f / 64.f);
    float dv = acc - m;
    float v = dv * dv;
    for (int o = 32; o >= 1; o >>= 1) v += __shfl_xor(v, o);
    v *= (1.f / 64.f);
    float out = dv * rsqrtf(v + 1e-5f) * lng[j] + lnb[j];
    int l2;
    if (permMode == 0) l2 = (l % 64) * 101 + (l / 64);   // (s,c)->(c,s)
    else               l2 = (l % 101) * 64 + (l / 101);  // (c,s)->(s,c)
    xnext[(size_t)l2 * 64 + j] = out;
    if (!doXz) return;
    // ---- next-layer xz for these 4 (permuted) rows: xz[l2] = out @ W_in
    s_out[w][j] = out;
    if (j == 0) s_l2[w] = l2;
    __syncthreads();
    float xa[4];
    #pragma unroll
    for (int r = 0; r < 4; r++) xa[r] = 0.f;
    for (int i = 0; i < 64; i++) {
        float wv = Win[i * 256 + tid];
        #pragma unroll
        for (int r = 0; r < 4; r++) xa[r] = fmaf(s_out[r][i], wv, xa[r]);
    }
    #pragma unroll
    for (int r = 0; r < 4; r++) xznext[(size_t)s_l2[r] * 256 + tid] = xa[r];
}

// ---------------- epilogue ----------------
__global__ void k_epilogue(const float* __restrict__ x, const float* __restrict__ Wfc,
                           const float* __restrict__ bfc, const float* __restrict__ ytrue,
                           const int* __restrict__ halfwin, const int* __restrict__ rows,
                           float* __restrict__ out) {
    int k = threadIdx.x;  // 64
    int hw = halfwin[0];
    int c = rows[k];
    const float* xr = x + ((size_t)hw * 64 + c) * 64;
    float acc = bfc[0];
    for (int i = 0; i < 64; i++) acc += xr[i] * Wfc[i];
    float s = 1.f / (1.f + expf(-acc));
    float r = 1.f - fabsf(ytrue[k] - s);
    out[k] = r;
}

extern "C" void kernel_launch(void* const* d_in, const int* in_sizes, int n_in,
                              void* d_out, int out_size, void* d_ws, size_t ws_size,
                              hipStream_t stream) {
    const float* DNA   = (const float*)d_in[0];
    const float* CpG   = (const float*)d_in[1];
    const float* cel   = (const float*)d_in[2];
    const float* pos   = (const float*)d_in[3];
    const float* ytrue = (const float*)d_in[4];
    const float* Wfcc  = (const float*)d_in[5];
    const float* bfcc  = (const float*)d_in[6];
    const float* Win   = (const float*)d_in[7];
    const float* convw = (const float*)d_in[8];
    const float* convb = (const float*)d_in[9];
    const float* Wxp   = (const float*)d_in[10];
    const float* Wdt   = (const float*)d_in[11];
    const float* bdt   = (const float*)d_in[12];
    const float* Alog  = (const float*)d_in[13];
    const float* Dres  = (const float*)d_in[14];
    const float* Wout  = (const float*)d_in[15];
    const float* lng   = (const float*)d_in[16];
    const float* lnb   = (const float*)d_in[17];
    const float* Wfc   = (const float*)d_in[18];
    const float* bfc   = (const float*)d_in[19];
    const int* halfwin = (const int*)d_in[20];
    const int* rows    = (const int*)d_in[21];

    float* ws = (float*)d_ws;
    size_t off = 0;
    float* x0  = ws + off; off += (size_t)L_SEQ * 64;
    float* x1  = ws + off; off += (size_t)L_SEQ * 64;
    float* xzA = ws + off; off += (size_t)L_SEQ * 256;
    float* xzB = ws + off; off += (size_t)L_SEQ * 256;
    float* xcb = ws + off; off += (size_t)2 * L_SEQ * 128;
    float* dtb = ws + off; off += (size_t)2 * L_SEQ * 128;
    float* BCb = ws + off; off += (size_t)2 * L_SEQ * 32;
    float* yb  = ws + off; off += (size_t)2 * L_SEQ * 128;
    float* cAb = ws + off; off += (size_t)2 * NCH * 2048;
    float* cBb = ws + off; off += (size_t)2 * NCH * 2048;

    k_embed<<<L_SEQ, 64, 0, stream>>>(DNA, CpG, cel, pos, Wfcc, bfcc, x0);

    float* xcur = x0;
    float* xnxt = x1;
    float* xzc  = xzA;
    float* xzn  = xzB;
    k_gemm_in<<<L_SEQ / 8, 256, 0, stream>>>(xcur, Win, xzc);
    for (int sb = 0; sb < 8; sb++) {
        k_convdt<<<L_SEQ / 16, 256, 0, stream>>>(xzc, convw, convb, Wxp, Wdt, bdt, xcb, dtb, BCb);
        k_scan1s<<<dim3(8, NCH, 2), 256, 0, stream>>>(dtb, xcb, BCb, Alog, cAb, cBb);
        k_scan3s<<<dim3(8, NCH, 2), 256, 0, stream>>>(dtb, xcb, BCb, Alog, Dres, cAb, cBb, yb);
        k_outln<<<L_SEQ / 4, 256, 0, stream>>>(xcur, yb, xzc, Wout, Win, lng, lnb, xnxt, xzn,
                                               (sb % 2 == 0) ? 0 : 1, (sb < 7) ? 1 : 0);
        float* tmp = xcur; xcur = xnxt; xnxt = tmp;
        float* tz = xzc; xzc = xzn; xzn = tz;
    }

    k_epilogue<<<1, 64, 0, stream>>>(xcur, Wfc, bfc, ytrue, halfwin, rows, (float*)d_out);
}